// Round 17
// baseline (823.577 us; speedup 1.0000x reference)
//
#include <hip/hip_runtime.h>
#include <hip/hip_bf16.h>

#define IN_DIM 32
#define HID 64
#define LN_EPS 1e-5f
#define BSH 3                 // 8 nodes per bucket
#define BCAP 1024             // fixed bucket capacity == sort LDS staging
#define CSH 10                // log2(BCAP)

typedef unsigned short ush;
typedef unsigned int u32;
typedef unsigned long long u64;
typedef __attribute__((ext_vector_type(8))) short bf16x8;
typedef __attribute__((ext_vector_type(4))) float f32x4;
typedef __attribute__((ext_vector_type(4))) unsigned int u32x4;

static __device__ __forceinline__ float b2f(u32 u) {
    union { u32 i; float f; } v; v.i = u << 16; return v.f;
}
// manual RNE (one-time kernels)
static __device__ __forceinline__ ush f2b(float f) {
    union { float f; u32 i; } v; v.f = f;
    u32 x = v.i;
    return (ush)((x + 0x7fffu + ((x >> 16) & 1u)) >> 16);
}
// hardware cast (hot path)
static __device__ __forceinline__ u32 f2bh(float f) {
    union { __hip_bfloat16 h; ush u; } v;
    v.h = __float2bfloat16(f);
    return (u32)v.u;
}

__global__ __launch_bounds__(256) void zero_i32(int* __restrict__ p, int n) {
    const int i = blockIdx.x * 256 + threadIdx.x;
    if (i < n) p[i] = 0;
}

__global__ __launch_bounds__(256) void zero16(uint4* __restrict__ p, int n16) {
    const int i = blockIdx.x * 256 + threadIdx.x;
    if (i < n16) p[i] = make_uint4(0u, 0u, 0u, 0u);
}

static __device__ __forceinline__ bool sniff_idx64(const int* idx) {
    int zc = 0;
    #pragma unroll
    for (int t = 0; t < 8; ++t) zc += (idx[2 * t + 1] == 0) ? 1 : 0;
    return zc >= 7;
}

// ---------------- weight packing + cursor init (merged, one launch) ----------------
__global__ __launch_bounds__(256) void pack_and_init(
    const float* __restrict__ W1, const float* __restrict__ W2,
    const float* __restrict__ W3, const float* __restrict__ W4,
    ush* __restrict__ pack, int* __restrict__ bcur, int NB)
{
    const int i = blockIdx.x * 256 + threadIdx.x;
    if (i < NB) bcur[i] = i << CSH;
    if (i >= 14336) return;
    const float* W; int base;
    if (i < 2048)       { W = W1; base = 0; }
    else if (i < 6144)  { W = W2; base = 2048; }
    else if (i < 10240) { W = W3; base = 6144; }
    else                { W = W4; base = 10240; }
    const int j = i - base;
    const int e = j & 7, l = (j >> 3) & 63, f = j >> 9;
    const int ct = f & 3, kc = f >> 2;
    const int k = kc * 32 + ((l >> 4) << 3) + e;
    const int col = ct * 16 + (l & 15);
    pack[i] = f2b(W[k * HID + col]);
}

// ---- legacy exact-CSR helpers (mid-tier fallback) ----

__global__ __launch_bounds__(256) void bucket_count(
    const int* __restrict__ idx, int* __restrict__ bcnt, int E, int N)
{
    const bool idx64 = sniff_idx64(idx);
    const int e = blockIdx.x * 256 + threadIdx.x;
    if (e >= E) return;
    int na, nb;
    if (idx64) { const int4 p = ((const int4*)idx)[e]; na = p.x; nb = p.z; }
    else       { const int2 p = ((const int2*)idx)[e]; na = p.x; nb = p.y; }
    na = min(max(na, 0), N - 1);
    nb = min(max(nb, 0), N - 1);
    atomicAdd(&bcnt[na >> BSH], 1);
    atomicAdd(&bcnt[nb >> BSH], 1);
}

__global__ __launch_bounds__(1024) void scan_excl2(
    int* __restrict__ a, int* __restrict__ b, int n)
{
    __shared__ int lds[1024];
    const int t = threadIdx.x;
    const int L = (n + 1023) >> 10;
    const int lo = t * L, hi = min(n, lo + L);
    int s = 0;
    for (int i = lo; i < hi; ++i) s += a[i];
    lds[t] = s;
    __syncthreads();
    #pragma unroll
    for (int d = 1; d < 1024; d <<= 1) {
        const int v = (t >= d) ? lds[t - d] : 0;
        __syncthreads();
        lds[t] += v;
        __syncthreads();
    }
    int run = lds[t] - s;
    for (int i = lo; i < hi; ++i) {
        const int c = a[i];
        a[i] = run; b[i] = run;
        run += c;
    }
}

// standalone append (mid-tier path only)
__global__ __launch_bounds__(256) void append_pairs(
    const int* __restrict__ idx, int* __restrict__ bcur,
    u32* __restrict__ buf, int E, int N)
{
    const bool idx64 = sniff_idx64(idx);
    const int e = blockIdx.x * 256 + threadIdx.x;
    if (e >= E) return;
    int na, nb;
    if (idx64) { const int4 p = ((const int4*)idx)[e]; na = p.x; nb = p.z; }
    else       { const int2 p = ((const int2*)idx)[e]; na = p.x; nb = p.y; }
    na = min(max(na, 0), N - 1);
    nb = min(max(nb, 0), N - 1);
    const int pa = atomicAdd(&bcur[na >> BSH], 1);
    buf[pa] = ((u32)(na & ((1 << BSH) - 1)) << 29) | (u32)e;
    const int pb = atomicAdd(&bcur[nb >> BSH], 1);
    buf[pb] = ((u32)(nb & ((1 << BSH) - 1)) << 29) | (u32)e;
}

// in-bucket counting sort; one wave per bucket. FIXED=1: bstart = b<<CSH.
template <int FIXED>
__global__ __launch_bounds__(256) void bucket_sort(
    const int* __restrict__ bstart, const int* __restrict__ bend,
    u32* __restrict__ buf, int* __restrict__ nstart, int NB, int N)
{
    __shared__ u32 stg[4][BCAP];
    const int tid = threadIdx.x, wave = tid >> 6, lane = tid & 63;
    const int b = blockIdx.x * 4 + wave;
    if (b >= NB) return;
    const int s = FIXED ? (b << CSH) : bstart[b];
    const int e = bend[b], len = e - s;
    const int node0 = b << BSH;

    if (len > BCAP) {   // pathological: leave unsorted, mark nodes
        if (lane < 8 && node0 + lane < N) nstart[node0 + lane] = -1;
        return;
    }

    for (int i = lane; i < len; i += 64) stg[wave][i] = buf[s + i];

    int c[8] = {0, 0, 0, 0, 0, 0, 0, 0};
    for (int i = lane; i < len; i += 64) ++c[stg[wave][i] >> 29];
    #pragma unroll
    for (int k = 0; k < 8; ++k) {
        int v = c[k];
        #pragma unroll
        for (int m = 1; m < 64; m <<= 1) v += __shfl_xor(v, m, 64);
        c[k] = v;
    }
    u32 run[8];
    {
        u32 acc = 0;
        #pragma unroll
        for (int k = 0; k < 8; ++k) { run[k] = acc; acc += (u32)c[k]; }
    }
    if (lane < 8 && node0 + lane < N) nstart[node0 + lane] = s + (int)run[lane];

    for (int i0 = 0; i0 < len; i0 += 64) {
        const int i = i0 + lane;
        const bool val = i < len;
        const u32 ent = val ? stg[wave][i] : 0u;
        const int k = (int)(ent >> 29);
        u32 pos = 0;
        #pragma unroll
        for (int kk = 0; kk < 8; ++kk) {
            const u64 m = __ballot(val && (k == kk));
            if (val && k == kk)
                pos = run[kk] + (u32)__popcll(m & ((1ull << lane) - 1ull));
            run[kk] += (u32)__popcll(m);
        }
        if (val) buf[s + pos] = ent;
    }
}

// ---- bf16 gather: half-wave entry split, lane = col-pair (u32 = 2 bf16) ----
template <int FIXED>
__global__ __launch_bounds__(256) void node_gather_bf(
    const int* __restrict__ nstart,
    const int* __restrict__ bstart, const int* __restrict__ bend,
    const u32* __restrict__ buf,
    const u32* __restrict__ ebf,          // [E][32] u32 (bf16 col-pairs)
    float* __restrict__ out_node, int N)
{
    const int w = (blockIdx.x * 256 + threadIdx.x) >> 6;
    const int lane = threadIdx.x & 63;
    if (w >= N) return;
    const int half = lane >> 5, j = lane & 31;
    const int b = w >> BSH;

    float ax = 0.f, ay = 0.f;
    const int s0 = nstart[w];
    if (s0 >= 0) {
        const bool lastInB = ((w & ((1 << BSH) - 1)) == ((1 << BSH) - 1)) || (w == N - 1);
        const int e0 = lastInB ? bend[b] : nstart[w + 1];
        int i = s0;
        for (; i + 16 <= e0; i += 16) {
            u32 ent[8];
            #pragma unroll
            for (int u = 0; u < 8; ++u) ent[u] = buf[i + half * 8 + u];
            u32 rv[8];
            #pragma unroll
            for (int u = 0; u < 8; ++u)
                rv[u] = ebf[(size_t)(ent[u] & 0x1FFFFFFFu) * 32 + j];
            #pragma unroll
            for (int u = 0; u < 8; ++u) {
                ax += b2f(rv[u] & 0xffffu);
                ay += b2f(rv[u] >> 16);
            }
        }
        for (int ii = i + half; ii < e0; ii += 2) {
            const u32 v = ebf[(size_t)(buf[ii] & 0x1FFFFFFFu) * 32 + j];
            ax += b2f(v & 0xffffu);
            ay += b2f(v >> 16);
        }
    } else {
        if (half == 0) {
            const u32 key = (u32)(w & ((1 << BSH) - 1)) << 29;
            const int s = FIXED ? (b << CSH) : bstart[b];
            const int e = bend[b];
            for (int i = s; i < e; ++i) {
                const u32 en = buf[i];
                if ((en & 0xE0000000u) == key) {
                    const u32 v = ebf[(size_t)(en & 0x1FFFFFFFu) * 32 + j];
                    ax += b2f(v & 0xffffu);
                    ay += b2f(v >> 16);
                }
            }
        }
    }
    ax += __shfl_xor(ax, 32, 64);
    ay += __shfl_xor(ay, 32, 64);
    if (half == 0) {
        float2 o; o.x = ax; o.y = ay;
        *(float2*)(out_node + (size_t)w * HID + 2 * j) = o;
    }
}

// ---- f32 gather (mid-tier fallback) ----
__global__ __launch_bounds__(256) void node_gather(
    const int* __restrict__ nstart,
    const int* __restrict__ bstart, const int* __restrict__ bend,
    const u32* __restrict__ buf,
    const float* __restrict__ edge_feat,
    float* __restrict__ out_node, int N)
{
    const int w = (blockIdx.x * 256 + threadIdx.x) >> 6;
    const int lane = threadIdx.x & 63;
    if (w >= N) return;
    const int b = w >> BSH;

    float acc = 0.f;
    const int s0 = nstart[w];
    if (s0 >= 0) {
        const bool lastInB = ((w & ((1 << BSH) - 1)) == ((1 << BSH) - 1)) || (w == N - 1);
        const int e0 = lastInB ? bend[b] : nstart[w + 1];
        int i = s0;
        for (; i + 16 <= e0; i += 16) {
            u32 ent[16];
            #pragma unroll
            for (int u = 0; u < 16; ++u) ent[u] = buf[i + u];
            float v[16];
            #pragma unroll
            for (int u = 0; u < 16; ++u)
                v[u] = edge_feat[(size_t)(ent[u] & 0x1FFFFFFFu) * HID + lane];
            #pragma unroll
            for (int u = 0; u < 16; ++u) acc += v[u];
        }
        for (; i < e0; ++i)
            acc += edge_feat[(size_t)(buf[i] & 0x1FFFFFFFu) * HID + lane];
    } else {
        const u32 key = (u32)(w & ((1 << BSH) - 1)) << 29;
        const int s = bstart[b], e = bend[b];
        for (int i = s; i < e; ++i) {
            const u32 en = buf[i];
            if ((en & 0xE0000000u) == key)
                acc += edge_feat[(size_t)(en & 0x1FFFFFFFu) * HID + lane];
        }
    }
    out_node[(size_t)w * HID + lane] = acc;
}

// ---------------- standalone pack (mid-tier path) ----------------
__global__ __launch_bounds__(256) void pack_weights(
    const float* __restrict__ W1, const float* __restrict__ W2,
    const float* __restrict__ W3, const float* __restrict__ W4,
    ush* __restrict__ pack)
{
    const int i = blockIdx.x * 256 + threadIdx.x;
    if (i >= 14336) return;
    const float* W; int base;
    if (i < 2048)       { W = W1; base = 0; }
    else if (i < 6144)  { W = W2; base = 2048; }
    else if (i < 10240) { W = W3; base = 6144; }
    else                { W = W4; base = 10240; }
    const int j = i - base;
    const int e = j & 7, l = (j >> 3) & 63, f = j >> 9;
    const int ct = f & 3, kc = f >> 2;
    const int k = kc * 32 + ((l >> 4) << 3) + e;
    const int col = ct * 16 + (l & 15);
    pack[i] = f2b(W[k * HID + col]);
}

// ---------------- MFMA MLP + LayerNorm: SWAPPED operands (A=weights, B=acts) ----------------
// D = W^T · h^T. Per-lane C: edge = lane&15, features mt*16 + lg*4 + r (4
// CONSECUTIVE features per mt in-lane) -> packed b64 LDS writes (4/layer vs 16),
// 2-shfl LN, float4 out_edge stores, ebf packed straight from registers.
// Weight pack is unchanged (A-frag(row=l15,k) == B-frag(col=l15,k) formula).
template <int APPEND>
__global__ __launch_bounds__(512, 6) void mlp_ln_mfma(
    const float* __restrict__ x,       // [E,32] f32
    const ush* __restrict__ packW,     // 14336 bf16
    const float* __restrict__ b1, const float* __restrict__ b2,
    const float* __restrict__ b3, const float* __restrict__ b4,
    const float* __restrict__ gamma, const float* __restrict__ beta,
    float* __restrict__ out_edge,      // [E,64] f32
    u32* __restrict__ ebf,             // [E][32] bf16 pairs
    int write_bf,
    const int* __restrict__ idx,       // APPEND only
    int* __restrict__ bcur,            // APPEND only
    u32* __restrict__ buf,             // APPEND only
    int E, int N)
{
    __shared__ float sB[6 * HID];                    // 1.5 KB
    __shared__ __align__(16) ush sW[14336];          // 28 KB
    __shared__ __align__(16) ush hbuf[8][16 * 72];   // 18 KB

    const int tid = threadIdx.x;
    const int wave = tid >> 6, lane = tid & 63;

    if (APPEND) {
        const int e = blockIdx.x * 128 + tid;
        if (tid < 128 && e < E) {
            const bool idx64 = sniff_idx64(idx);
            int na, nb;
            if (idx64) { const int4 p = ((const int4*)idx)[e]; na = p.x; nb = p.z; }
            else       { const int2 p = ((const int2*)idx)[e]; na = p.x; nb = p.y; }
            na = min(max(na, 0), N - 1);
            nb = min(max(nb, 0), N - 1);
            const int pa = atomicAdd(&bcur[na >> BSH], 1);
            buf[pa] = ((u32)(na & ((1 << BSH) - 1)) << 29) | (u32)e;
            const int pb = atomicAdd(&bcur[nb >> BSH], 1);
            buf[pb] = ((u32)(nb & ((1 << BSH) - 1)) << 29) | (u32)e;
        }
    }

    {   // stage weights: 1792 uint4 across 512 threads
        const uint4* src = (const uint4*)packW;
        uint4* dst = (uint4*)sW;
        #pragma unroll
        for (int i = 0; i < 4; ++i) {
            const int o = tid + i * 512;
            if (o < 1792) dst[o] = src[o];
        }
    }
    if (tid < HID) {
        sB[tid]           = b1[tid];
        sB[HID + tid]     = b2[tid];
        sB[2 * HID + tid] = b3[tid];
        sB[3 * HID + tid] = b4[tid];
        sB[4 * HID + tid] = gamma[tid];
        sB[5 * HID + tid] = beta[tid];
    }
    __syncthreads();

    const bf16x8* wfrag = (const bf16x8*)sW;

    ush* hb = &hbuf[wave][0];
    const int l15 = lane & 15, lg = lane >> 4;

    const int rowBase = blockIdx.x * 128 + wave * 16;

    // B operand (x): lane = edge l15, k = lg*8+e
    const int rr = min(rowBase + l15, E - 1);
    const f32x4* xp = (const f32x4*)(x + (size_t)rr * IN_DIM + lg * 8);
    const f32x4 xa = __builtin_nontemporal_load(xp);
    const f32x4 xb = __builtin_nontemporal_load(xp + 1);
    bf16x8 aL1;
    aL1[0] = (short)f2bh(xa[0]); aL1[1] = (short)f2bh(xa[1]);
    aL1[2] = (short)f2bh(xa[2]); aL1[3] = (short)f2bh(xa[3]);
    aL1[4] = (short)f2bh(xb[0]); aL1[5] = (short)f2bh(xb[1]);
    aL1[6] = (short)f2bh(xb[2]); aL1[7] = (short)f2bh(xb[3]);

    f32x4 acc[4];

    // ---- layer 1 (K=32): A = W1 frags, B = x ----
    #pragma unroll
    for (int mt = 0; mt < 4; ++mt) {
        f32x4 c = *(const f32x4*)&sB[0 * HID + mt * 16 + lg * 4];   // bias (per-row)
        const bf16x8 wf = wfrag[mt * 64 + lane];
        c = __builtin_amdgcn_mfma_f32_16x16x32_bf16(wf, aL1, c, 0, 0, 0);
        acc[mt] = c;
    }

    // relu + packed b64 writes to LDS [edge l15][feat mt*16+lg*4 .. +3]
    #pragma unroll
    for (int mt = 0; mt < 4; ++mt) {
        const float v0 = fmaxf(acc[mt][0], 0.f);
        const float v1 = fmaxf(acc[mt][1], 0.f);
        const float v2 = fmaxf(acc[mt][2], 0.f);
        const float v3 = fmaxf(acc[mt][3], 0.f);
        uint2 pk;
        pk.x = f2bh(v0) | (f2bh(v1) << 16);
        pk.y = f2bh(v2) | (f2bh(v3) << 16);
        *(uint2*)&hb[l15 * 72 + mt * 16 + lg * 4] = pk;
    }

    #define LAYER(WBASE, BIDX, RELU_) do {                                  \
        const bf16x8 a0 = *(const bf16x8*)&hb[l15 * 72 + 0 + lg * 8];       \
        const bf16x8 a1 = *(const bf16x8*)&hb[l15 * 72 + 32 + lg * 8];      \
        _Pragma("unroll")                                                   \
        for (int mt = 0; mt < 4; ++mt) {                                    \
            f32x4 c = *(const f32x4*)&sB[(BIDX) * HID + mt * 16 + lg * 4];  \
            const bf16x8 wlo = wfrag[(WBASE) + mt * 64 + lane];             \
            const bf16x8 whi = wfrag[(WBASE) + (4 + mt) * 64 + lane];       \
            c = __builtin_amdgcn_mfma_f32_16x16x32_bf16(wlo, a0, c, 0, 0, 0); \
            c = __builtin_amdgcn_mfma_f32_16x16x32_bf16(whi, a1, c, 0, 0, 0); \
            acc[mt] = c;                                                    \
        }                                                                   \
        if (RELU_) {                                                        \
            _Pragma("unroll")                                               \
            for (int mt = 0; mt < 4; ++mt) {                                \
                const float v0 = fmaxf(acc[mt][0], 0.f);                    \
                const float v1 = fmaxf(acc[mt][1], 0.f);                    \
                const float v2 = fmaxf(acc[mt][2], 0.f);                    \
                const float v3 = fmaxf(acc[mt][3], 0.f);                    \
                uint2 pk;                                                   \
                pk.x = f2bh(v0) | (f2bh(v1) << 16);                         \
                pk.y = f2bh(v2) | (f2bh(v3) << 16);                         \
                *(uint2*)&hb[l15 * 72 + mt * 16 + lg * 4] = pk;             \
            }                                                               \
        }                                                                   \
    } while (0)

    LAYER(256, 1, 1);    // W2 at frag offset 2048/8 = 256
    LAYER(768, 2, 1);    // W3
    LAYER(1280, 3, 0);   // W4
    #undef LAYER

    // ---- LayerNorm: per-lane partial over 16 in-lane values, 2-shfl reduce ----
    float s = 0.f, q = 0.f;
    #pragma unroll
    for (int mt = 0; mt < 4; ++mt)
        #pragma unroll
        for (int r = 0; r < 4; ++r) {
            const float v = acc[mt][r];
            s += v; q += v * v;
        }
    s += __shfl_xor(s, 16, 64); q += __shfl_xor(q, 16, 64);
    s += __shfl_xor(s, 32, 64); q += __shfl_xor(q, 32, 64);
    const float mu = s * (1.0f / HID);
    const float varr = fmaxf(q * (1.0f / HID) - mu * mu, 0.f);
    const float inv = rsqrtf(varr + LN_EPS);

    const int row = rowBase + l15;
    if (row < E) {
        float* op = out_edge + (size_t)row * HID;
        u32* ep = ebf + (size_t)row * 32;
        #pragma unroll
        for (int mt = 0; mt < 4; ++mt) {
            const f32x4 g4 = *(const f32x4*)&sB[4 * HID + mt * 16 + lg * 4];
            const f32x4 bt4 = *(const f32x4*)&sB[5 * HID + mt * 16 + lg * 4];
            f32x4 o;
            #pragma unroll
            for (int r = 0; r < 4; ++r)
                o[r] = g4[r] * (acc[mt][r] - mu) * inv + bt4[r];
            *(f32x4*)(op + mt * 16 + lg * 4) = o;    // float4, 64B segments
            if (write_bf) {
                uint2 pk;
                pk.x = f2bh(o[0]) | (f2bh(o[1]) << 16);
                pk.y = f2bh(o[2]) | (f2bh(o[3]) << 16);
                *(uint2*)(ep + mt * 8 + lg * 2) = pk;
            }
        }
    }
}

// ---------------- fallback: VALU kernel with atomics (ws tiny) ----------------
__global__ __launch_bounds__(256) void mlp_ln_scatter_fb(
    const float* __restrict__ x, const int* __restrict__ idx,
    const float* __restrict__ W1, const float* __restrict__ b1,
    const float* __restrict__ W2, const float* __restrict__ b2,
    const float* __restrict__ W3, const float* __restrict__ b3,
    const float* __restrict__ W4, const float* __restrict__ b4,
    const float* __restrict__ gamma, const float* __restrict__ beta,
    float* __restrict__ out_edge, float* __restrict__ node_acc, int E, int N)
{
    __shared__ float sW1[IN_DIM * HID];
    __shared__ float sW2[HID * HID];
    __shared__ float sW3[HID * HID];
    __shared__ float sW4[HID * HID];
    __shared__ float sB[6 * HID];
    const int tid = threadIdx.x;
    {
        const float4* W1v = (const float4*)W1;
        float4* s1 = (float4*)sW1;
        for (int i = tid; i < IN_DIM * HID / 4; i += 256) s1[i] = W1v[i];
        const float4* W2v = (const float4*)W2;
        const float4* W3v = (const float4*)W3;
        const float4* W4v = (const float4*)W4;
        float4* s2 = (float4*)sW2; float4* s3 = (float4*)sW3; float4* s4 = (float4*)sW4;
        for (int i = tid; i < HID * HID / 4; i += 256) { s2[i] = W2v[i]; s3[i] = W3v[i]; s4[i] = W4v[i]; }
        if (tid < HID) {
            sB[tid] = b1[tid]; sB[HID + tid] = b2[tid]; sB[2 * HID + tid] = b3[tid];
            sB[3 * HID + tid] = b4[tid]; sB[4 * HID + tid] = gamma[tid]; sB[5 * HID + tid] = beta[tid];
        }
    }
    __syncthreads();
    const int e = blockIdx.x * 256 + tid;
    if (e >= E) return;
    float h0[IN_DIM];
    {
        const float4* xv = (const float4*)(x + (size_t)e * IN_DIM);
        #pragma unroll
        for (int c = 0; c < 8; ++c) {
            const float4 v = xv[c];
            h0[c * 4 + 0] = v.x; h0[c * 4 + 1] = v.y; h0[c * 4 + 2] = v.z; h0[c * 4 + 3] = v.w;
        }
    }
    float a[HID], h[HID];
    #pragma unroll
    for (int j = 0; j < HID; ++j) a[j] = sB[j];
    #pragma unroll
    for (int k = 0; k < IN_DIM; ++k) {
        const float hk = h0[k];
        #pragma unroll
        for (int j = 0; j < HID; ++j) a[j] = fmaf(hk, sW1[k * HID + j], a[j]);
    }
    #pragma unroll
    for (int j = 0; j < HID; ++j) h[j] = a[j] > 0.f ? a[j] : 0.f;
    #pragma unroll
    for (int j = 0; j < HID; ++j) a[j] = sB[HID + j];
    #pragma unroll
    for (int k = 0; k < HID; ++k) {
        const float hk = h[k];
        #pragma unroll
        for (int j = 0; j < HID; ++j) a[j] = fmaf(hk, sW2[k * HID + j], a[j]);
    }
    #pragma unroll
    for (int j = 0; j < HID; ++j) h[j] = a[j] > 0.f ? a[j] : 0.f;
    #pragma unroll
    for (int j = 0; j < HID; ++j) a[j] = sB[2 * HID + j];
    #pragma unroll
    for (int k = 0; k < HID; ++k) {
        const float hk = h[k];
        #pragma unroll
        for (int j = 0; j < HID; ++j) a[j] = fmaf(hk, sW3[k * HID + j], a[j]);
    }
    #pragma unroll
    for (int j = 0; j < HID; ++j) h[j] = a[j] > 0.f ? a[j] : 0.f;
    #pragma unroll
    for (int j = 0; j < HID; ++j) a[j] = sB[3 * HID + j];
    #pragma unroll
    for (int k = 0; k < HID; ++k) {
        const float hk = h[k];
        #pragma unroll
        for (int j = 0; j < HID; ++j) a[j] = fmaf(hk, sW4[k * HID + j], a[j]);
    }
    float s = 0.f;
    #pragma unroll
    for (int j = 0; j < HID; ++j) s += a[j];
    const float mu = s * (1.0f / HID);
    float s2 = 0.f;
    #pragma unroll
    for (int j = 0; j < HID; ++j) { const float d = a[j] - mu; s2 += d * d; }
    const float inv = rsqrtf(s2 * (1.0f / HID) + LN_EPS);
    #pragma unroll
    for (int j = 0; j < HID; ++j)
        a[j] = sB[4 * HID + j] * ((a[j] - mu) * inv) + sB[5 * HID + j];
    {
        float4* oe = (float4*)(out_edge + (size_t)e * HID);
        #pragma unroll
        for (int c = 0; c < 16; ++c)
            oe[c] = make_float4(a[c * 4], a[c * 4 + 1], a[c * 4 + 2], a[c * 4 + 3]);
    }
    const bool idx64 = sniff_idx64(idx);
    int na, nb;
    if (idx64) { na = idx[4 * (size_t)e]; nb = idx[4 * (size_t)e + 2]; }
    else       { na = idx[2 * (size_t)e]; nb = idx[2 * (size_t)e + 1]; }
    na = min(max(na, 0), N - 1);
    nb = min(max(nb, 0), N - 1);
    float* pa = node_acc + (size_t)na * HID;
    float* pb = node_acc + (size_t)nb * HID;
    #pragma unroll
    for (int j = 0; j < HID; ++j) {
        unsafeAtomicAdd(pa + j, a[j]);
        unsafeAtomicAdd(pb + j, a[j]);
    }
}

extern "C" void kernel_launch(void* const* d_in, const int* in_sizes, int n_in,
                              void* d_out, int out_size, void* d_ws, size_t ws_size,
                              hipStream_t stream) {
    const float* x     = (const float*)d_in[0];
    const int*   idx   = (const int*)d_in[1];
    const float* W1    = (const float*)d_in[3];
    const float* b1    = (const float*)d_in[4];
    const float* W2    = (const float*)d_in[5];
    const float* b2    = (const float*)d_in[6];
    const float* W3    = (const float*)d_in[7];
    const float* b3    = (const float*)d_in[8];
    const float* W4    = (const float*)d_in[9];
    const float* b4    = (const float*)d_in[10];
    const float* gamma = (const float*)d_in[11];
    const float* beta  = (const float*)d_in[12];

    const int E = in_sizes[0] / IN_DIM;
    const int N = out_size / HID - E;
    const int NB = (N + (1 << BSH) - 1) >> BSH;   // 8-node buckets

    float* out_node = (float*)d_out;
    float* out_edge = out_node + (size_t)N * HID;

    // ---- primary (fixed-capacity) layout:
    //   pack(32KB) | bcur[NB] | nstart[N] | buf[NB<<CSH] | ebf[E*32 u32]
    const size_t bcurOffF   = 32768;
    const size_t nstartOffF = bcurOffF + (((size_t)NB * 4 + 255) & ~255ull);
    const size_t bufOffF    = nstartOffF + (((size_t)N * 4 + 255) & ~255ull);
    const size_t ebfOffF    = (bufOffF + ((size_t)NB << CSH) * 4 + 255) & ~255ull;
    const size_t need_fixed = ebfOffF + (size_t)E * 32 * sizeof(u32);

    // ---- mid-tier (exact CSR layout)
    const size_t bstartOff = 32768;
    const size_t bcurOff   = bstartOff + (((size_t)NB * 4 + 255) & ~255ull);
    const size_t nstartOff = bcurOff + (((size_t)NB * 4 + 255) & ~255ull);
    const size_t bufOff    = nstartOff + (((size_t)N * 4 + 255) & ~255ull);
    const size_t ebfOff    = (bufOff + (size_t)2 * E * sizeof(u32) + 255) & ~255ull;
    const size_t need_base = bufOff + (size_t)2 * E * sizeof(u32);
    const size_t need_bf   = ebfOff + (size_t)E * 32 * sizeof(u32);

    if (ws_size >= need_fixed) {
        // ---------- fixed-capacity path, append fused into MLP ----------
        ush* pack   = (ush*)d_ws;
        int* bcur   = (int*)((char*)d_ws + bcurOffF);
        int* nstart = (int*)((char*)d_ws + nstartOffF);
        u32* buf    = (u32*)((char*)d_ws + bufOffF);
        u32* ebf    = (u32*)((char*)d_ws + ebfOffF);

        pack_and_init<<<(14336 + 255) / 256, 256, 0, stream>>>(
            W1, W2, W3, W4, pack, bcur, NB);
        mlp_ln_mfma<1><<<(E + 127) / 128, 512, 0, stream>>>(
            x, pack, b1, b2, b3, b4, gamma, beta, out_edge, ebf, 1,
            idx, bcur, buf, E, N);
        bucket_sort<1><<<(NB + 3) / 4, 256, 0, stream>>>(
            nullptr, bcur, buf, nstart, NB, N);
        node_gather_bf<1><<<(N * 64 + 255) / 256, 256, 0, stream>>>(
            nstart, nullptr, bcur, buf, ebf, out_node, N);
    } else if (ws_size >= need_base) {
        // ---------- exact-CSR path ----------
        ush* pack   = (ush*)d_ws;
        int* bstart = (int*)((char*)d_ws + bstartOff);
        int* bcur   = (int*)((char*)d_ws + bcurOff);
        int* nstart = (int*)((char*)d_ws + nstartOff);
        u32* buf    = (u32*)((char*)d_ws + bufOff);
        u32* ebf    = (u32*)((char*)d_ws + ebfOff);
        const int use_bf = (ws_size >= need_bf) ? 1 : 0;

        pack_weights<<<(14336 + 255) / 256, 256, 0, stream>>>(W1, W2, W3, W4, pack);
        zero_i32<<<(NB + 255) / 256, 256, 0, stream>>>(bstart, NB);
        bucket_count<<<(E + 255) / 256, 256, 0, stream>>>(idx, bstart, E, N);
        scan_excl2<<<1, 1024, 0, stream>>>(bstart, bcur, NB);
        append_pairs<<<(E + 255) / 256, 256, 0, stream>>>(idx, bcur, buf, E, N);
        bucket_sort<0><<<(NB + 3) / 4, 256, 0, stream>>>(bstart, bcur, buf, nstart, NB, N);
        mlp_ln_mfma<0><<<(E + 127) / 128, 512, 0, stream>>>(
            x, pack, b1, b2, b3, b4, gamma, beta, out_edge, ebf, use_bf,
            nullptr, nullptr, nullptr, E, N);
        if (use_bf) {
            node_gather_bf<0><<<(N * 64 + 255) / 256, 256, 0, stream>>>(
                nstart, bstart, bcur, buf, ebf, out_node, N);
        } else {
            node_gather<<<(N * 64 + 255) / 256, 256, 0, stream>>>(
                nstart, bstart, bcur, buf, out_edge, out_node, N);
        }
    } else {
        const int n16 = (int)(((size_t)N * HID * sizeof(float)) / 16);
        zero16<<<(n16 + 255) / 256, 256, 0, stream>>>((uint4*)out_node, n16);
        mlp_ln_scatter_fb<<<(E + 255) / 256, 256, 0, stream>>>(
            x, idx, W1, b1, W2, b2, W3, b3, W4, b4, gamma, beta,
            out_edge, out_node, E, N);
    }
}

// Round 18
// 704.970 us; speedup vs baseline: 1.1682x; 1.1682x over previous
//
#include <hip/hip_runtime.h>
#include <hip/hip_bf16.h>

#define IN_DIM 32
#define HID 64
#define LN_EPS 1e-5f
#define BSH 3                 // 8 nodes per bucket
#define BCAP 1024             // fixed bucket capacity == sort LDS staging
#define CSH 10                // log2(BCAP)

typedef unsigned short ush;
typedef unsigned int u32;
typedef unsigned long long u64;
typedef __attribute__((ext_vector_type(8))) short bf16x8;
typedef __attribute__((ext_vector_type(4))) float f32x4;
typedef __attribute__((ext_vector_type(4))) unsigned int u32x4;

static __device__ __forceinline__ float b2f(u32 u) {
    union { u32 i; float f; } v; v.i = u << 16; return v.f;
}
// manual RNE (one-time kernels)
static __device__ __forceinline__ ush f2b(float f) {
    union { float f; u32 i; } v; v.f = f;
    u32 x = v.i;
    return (ush)((x + 0x7fffu + ((x >> 16) & 1u)) >> 16);
}
// hardware cast (hot path)
static __device__ __forceinline__ u32 f2bh(float f) {
    union { __hip_bfloat16 h; ush u; } v;
    v.h = __float2bfloat16(f);
    return (u32)v.u;
}

__global__ __launch_bounds__(256) void zero_i32(int* __restrict__ p, int n) {
    const int i = blockIdx.x * 256 + threadIdx.x;
    if (i < n) p[i] = 0;
}

__global__ __launch_bounds__(256) void zero16(uint4* __restrict__ p, int n16) {
    const int i = blockIdx.x * 256 + threadIdx.x;
    if (i < n16) p[i] = make_uint4(0u, 0u, 0u, 0u);
}

static __device__ __forceinline__ bool sniff_idx64(const int* idx) {
    int zc = 0;
    #pragma unroll
    for (int t = 0; t < 8; ++t) zc += (idx[2 * t + 1] == 0) ? 1 : 0;
    return zc >= 7;
}

// ---------------- weight packing + cursor init (merged, one launch) ----------------
__global__ __launch_bounds__(256) void pack_and_init(
    const float* __restrict__ W1, const float* __restrict__ W2,
    const float* __restrict__ W3, const float* __restrict__ W4,
    ush* __restrict__ pack, int* __restrict__ bcur, int NB)
{
    const int i = blockIdx.x * 256 + threadIdx.x;
    if (i < NB) bcur[i] = i << CSH;
    if (i >= 14336) return;
    const float* W; int base;
    if (i < 2048)       { W = W1; base = 0; }
    else if (i < 6144)  { W = W2; base = 2048; }
    else if (i < 10240) { W = W3; base = 6144; }
    else                { W = W4; base = 10240; }
    const int j = i - base;
    const int e = j & 7, l = (j >> 3) & 63, f = j >> 9;
    const int ct = f & 3, kc = f >> 2;
    const int k = kc * 32 + ((l >> 4) << 3) + e;
    const int col = ct * 16 + (l & 15);
    pack[i] = f2b(W[k * HID + col]);
}

// ---- legacy exact-CSR helpers (mid-tier fallback) ----

__global__ __launch_bounds__(256) void bucket_count(
    const int* __restrict__ idx, int* __restrict__ bcnt, int E, int N)
{
    const bool idx64 = sniff_idx64(idx);
    const int e = blockIdx.x * 256 + threadIdx.x;
    if (e >= E) return;
    int na, nb;
    if (idx64) { const int4 p = ((const int4*)idx)[e]; na = p.x; nb = p.z; }
    else       { const int2 p = ((const int2*)idx)[e]; na = p.x; nb = p.y; }
    na = min(max(na, 0), N - 1);
    nb = min(max(nb, 0), N - 1);
    atomicAdd(&bcnt[na >> BSH], 1);
    atomicAdd(&bcnt[nb >> BSH], 1);
}

__global__ __launch_bounds__(1024) void scan_excl2(
    int* __restrict__ a, int* __restrict__ b, int n)
{
    __shared__ int lds[1024];
    const int t = threadIdx.x;
    const int L = (n + 1023) >> 10;
    const int lo = t * L, hi = min(n, lo + L);
    int s = 0;
    for (int i = lo; i < hi; ++i) s += a[i];
    lds[t] = s;
    __syncthreads();
    #pragma unroll
    for (int d = 1; d < 1024; d <<= 1) {
        const int v = (t >= d) ? lds[t - d] : 0;
        __syncthreads();
        lds[t] += v;
        __syncthreads();
    }
    int run = lds[t] - s;
    for (int i = lo; i < hi; ++i) {
        const int c = a[i];
        a[i] = run; b[i] = run;
        run += c;
    }
}

// standalone append (mid-tier path only)
__global__ __launch_bounds__(256) void append_pairs(
    const int* __restrict__ idx, int* __restrict__ bcur,
    u32* __restrict__ buf, int E, int N)
{
    const bool idx64 = sniff_idx64(idx);
    const int e = blockIdx.x * 256 + threadIdx.x;
    if (e >= E) return;
    int na, nb;
    if (idx64) { const int4 p = ((const int4*)idx)[e]; na = p.x; nb = p.z; }
    else       { const int2 p = ((const int2*)idx)[e]; na = p.x; nb = p.y; }
    na = min(max(na, 0), N - 1);
    nb = min(max(nb, 0), N - 1);
    const int pa = atomicAdd(&bcur[na >> BSH], 1);
    buf[pa] = ((u32)(na & ((1 << BSH) - 1)) << 29) | (u32)e;
    const int pb = atomicAdd(&bcur[nb >> BSH], 1);
    buf[pb] = ((u32)(nb & ((1 << BSH) - 1)) << 29) | (u32)e;
}

// in-bucket counting sort (mid-tier path); one wave per bucket.
__global__ __launch_bounds__(256) void bucket_sort(
    const int* __restrict__ bstart, const int* __restrict__ bend,
    u32* __restrict__ buf, int* __restrict__ nstart, int NB, int N)
{
    __shared__ u32 stg[4][BCAP];
    const int tid = threadIdx.x, wave = tid >> 6, lane = tid & 63;
    const int b = blockIdx.x * 4 + wave;
    if (b >= NB) return;
    const int s = bstart[b];
    const int e = bend[b], len = e - s;
    const int node0 = b << BSH;

    if (len > BCAP) {
        if (lane < 8 && node0 + lane < N) nstart[node0 + lane] = -1;
        return;
    }

    for (int i = lane; i < len; i += 64) stg[wave][i] = buf[s + i];

    int c[8] = {0, 0, 0, 0, 0, 0, 0, 0};
    for (int i = lane; i < len; i += 64) ++c[stg[wave][i] >> 29];
    #pragma unroll
    for (int k = 0; k < 8; ++k) {
        int v = c[k];
        #pragma unroll
        for (int m = 1; m < 64; m <<= 1) v += __shfl_xor(v, m, 64);
        c[k] = v;
    }
    u32 run[8];
    {
        u32 acc = 0;
        #pragma unroll
        for (int k = 0; k < 8; ++k) { run[k] = acc; acc += (u32)c[k]; }
    }
    if (lane < 8 && node0 + lane < N) nstart[node0 + lane] = s + (int)run[lane];

    for (int i0 = 0; i0 < len; i0 += 64) {
        const int i = i0 + lane;
        const bool val = i < len;
        const u32 ent = val ? stg[wave][i] : 0u;
        const int k = (int)(ent >> 29);
        u32 pos = 0;
        #pragma unroll
        for (int kk = 0; kk < 8; ++kk) {
            const u64 m = __ballot(val && (k == kk));
            if (val && k == kk)
                pos = run[kk] + (u32)__popcll(m & ((1ull << lane) - 1ull));
            run[kk] += (u32)__popcll(m);
        }
        if (val) buf[s + pos] = ent;
    }
}

// ---------------- FUSED in-LDS sort + gather (primary path) ----------------
// One block per bucket: 512 thr = 8 waves. Stage the bucket segment once,
// wave 0 counting-sorts it into LDS, then wave w gathers node (b*8+w).
__global__ __launch_bounds__(512) void sort_gather_bf(
    const int* __restrict__ bend,     // bcur after append == segment ends
    const u32* __restrict__ buf,
    const u32* __restrict__ ebf,      // [E][32] u32 (bf16 col-pairs)
    float* __restrict__ out_node, int NB, int N)
{
    __shared__ u32 stg[BCAP];         // 4 KB raw entries
    __shared__ u32 srt[BCAP];         // 4 KB sorted entries
    __shared__ int snst[9];           // per-node segment starts + total

    const int tid = threadIdx.x, wave = tid >> 6, lane = tid & 63;
    const int b = blockIdx.x;
    const int s = b << CSH;
    const int len = min(bend[b] - s, BCAP);   // fixed-capacity invariant
    const int node0 = b << BSH;

    for (int i = tid; i < len; i += 512) stg[i] = buf[s + i];
    __syncthreads();

    if (wave == 0) {
        int c[8] = {0, 0, 0, 0, 0, 0, 0, 0};
        for (int i = lane; i < len; i += 64) ++c[stg[i] >> 29];
        #pragma unroll
        for (int k = 0; k < 8; ++k) {
            int v = c[k];
            #pragma unroll
            for (int m = 1; m < 64; m <<= 1) v += __shfl_xor(v, m, 64);
            c[k] = v;
        }
        u32 run[8];
        {
            u32 acc = 0;
            #pragma unroll
            for (int k = 0; k < 8; ++k) { run[k] = acc; acc += (u32)c[k]; }
        }
        if (lane == 0) {
            #pragma unroll
            for (int k = 0; k < 8; ++k) snst[k] = (int)run[k];
            snst[8] = len;
        }
        for (int i0 = 0; i0 < len; i0 += 64) {
            const int i = i0 + lane;
            const bool val = i < len;
            const u32 ent = val ? stg[i] : 0u;
            const int k = (int)(ent >> 29);
            u32 pos = 0;
            #pragma unroll
            for (int kk = 0; kk < 8; ++kk) {
                const u64 m = __ballot(val && (k == kk));
                if (val && k == kk)
                    pos = run[kk] + (u32)__popcll(m & ((1ull << lane) - 1ull));
                run[kk] += (u32)__popcll(m);
            }
            if (val) srt[pos] = ent;
        }
    }
    __syncthreads();

    const int w = node0 + wave;
    if (w >= N) return;
    const int half = lane >> 5, j = lane & 31;
    const int s0 = snst[wave], e0 = snst[wave + 1];

    float ax = 0.f, ay = 0.f;
    int i = s0;
    for (; i + 16 <= e0; i += 16) {
        u32 ent[8];
        #pragma unroll
        for (int u = 0; u < 8; ++u) ent[u] = srt[i + half * 8 + u];
        u32 rv[8];
        #pragma unroll
        for (int u = 0; u < 8; ++u)
            rv[u] = ebf[(size_t)(ent[u] & 0x1FFFFFFFu) * 32 + j];
        #pragma unroll
        for (int u = 0; u < 8; ++u) {
            ax += b2f(rv[u] & 0xffffu);
            ay += b2f(rv[u] >> 16);
        }
    }
    for (int ii = i + half; ii < e0; ii += 2) {
        const u32 v = ebf[(size_t)(srt[ii] & 0x1FFFFFFFu) * 32 + j];
        ax += b2f(v & 0xffffu);
        ay += b2f(v >> 16);
    }
    ax += __shfl_xor(ax, 32, 64);
    ay += __shfl_xor(ay, 32, 64);
    if (half == 0) {
        float2 o; o.x = ax; o.y = ay;
        *(float2*)(out_node + (size_t)w * HID + 2 * j) = o;
    }
}

// ---- bf16 gather (mid-tier path, exact-CSR offsets) ----
__global__ __launch_bounds__(256) void node_gather_bf(
    const int* __restrict__ nstart,
    const int* __restrict__ bstart, const int* __restrict__ bend,
    const u32* __restrict__ buf,
    const u32* __restrict__ ebf,
    float* __restrict__ out_node, int N)
{
    const int w = (blockIdx.x * 256 + threadIdx.x) >> 6;
    const int lane = threadIdx.x & 63;
    if (w >= N) return;
    const int half = lane >> 5, j = lane & 31;
    const int b = w >> BSH;

    float ax = 0.f, ay = 0.f;
    const int s0 = nstart[w];
    if (s0 >= 0) {
        const bool lastInB = ((w & ((1 << BSH) - 1)) == ((1 << BSH) - 1)) || (w == N - 1);
        const int e0 = lastInB ? bend[b] : nstart[w + 1];
        int i = s0;
        for (; i + 16 <= e0; i += 16) {
            u32 ent[8];
            #pragma unroll
            for (int u = 0; u < 8; ++u) ent[u] = buf[i + half * 8 + u];
            u32 rv[8];
            #pragma unroll
            for (int u = 0; u < 8; ++u)
                rv[u] = ebf[(size_t)(ent[u] & 0x1FFFFFFFu) * 32 + j];
            #pragma unroll
            for (int u = 0; u < 8; ++u) {
                ax += b2f(rv[u] & 0xffffu);
                ay += b2f(rv[u] >> 16);
            }
        }
        for (int ii = i + half; ii < e0; ii += 2) {
            const u32 v = ebf[(size_t)(buf[ii] & 0x1FFFFFFFu) * 32 + j];
            ax += b2f(v & 0xffffu);
            ay += b2f(v >> 16);
        }
    } else {
        if (half == 0) {
            const u32 key = (u32)(w & ((1 << BSH) - 1)) << 29;
            const int s = bstart[b], e = bend[b];
            for (int i = s; i < e; ++i) {
                const u32 en = buf[i];
                if ((en & 0xE0000000u) == key) {
                    const u32 v = ebf[(size_t)(en & 0x1FFFFFFFu) * 32 + j];
                    ax += b2f(v & 0xffffu);
                    ay += b2f(v >> 16);
                }
            }
        }
    }
    ax += __shfl_xor(ax, 32, 64);
    ay += __shfl_xor(ay, 32, 64);
    if (half == 0) {
        float2 o; o.x = ax; o.y = ay;
        *(float2*)(out_node + (size_t)w * HID + 2 * j) = o;
    }
}

// ---- f32 gather (mid-tier fallback) ----
__global__ __launch_bounds__(256) void node_gather(
    const int* __restrict__ nstart,
    const int* __restrict__ bstart, const int* __restrict__ bend,
    const u32* __restrict__ buf,
    const float* __restrict__ edge_feat,
    float* __restrict__ out_node, int N)
{
    const int w = (blockIdx.x * 256 + threadIdx.x) >> 6;
    const int lane = threadIdx.x & 63;
    if (w >= N) return;
    const int b = w >> BSH;

    float acc = 0.f;
    const int s0 = nstart[w];
    if (s0 >= 0) {
        const bool lastInB = ((w & ((1 << BSH) - 1)) == ((1 << BSH) - 1)) || (w == N - 1);
        const int e0 = lastInB ? bend[b] : nstart[w + 1];
        int i = s0;
        for (; i + 16 <= e0; i += 16) {
            u32 ent[16];
            #pragma unroll
            for (int u = 0; u < 16; ++u) ent[u] = buf[i + u];
            float v[16];
            #pragma unroll
            for (int u = 0; u < 16; ++u)
                v[u] = edge_feat[(size_t)(ent[u] & 0x1FFFFFFFu) * HID + lane];
            #pragma unroll
            for (int u = 0; u < 16; ++u) acc += v[u];
        }
        for (; i < e0; ++i)
            acc += edge_feat[(size_t)(buf[i] & 0x1FFFFFFFu) * HID + lane];
    } else {
        const u32 key = (u32)(w & ((1 << BSH) - 1)) << 29;
        const int s = bstart[b], e = bend[b];
        for (int i = s; i < e; ++i) {
            const u32 en = buf[i];
            if ((en & 0xE0000000u) == key)
                acc += edge_feat[(size_t)(en & 0x1FFFFFFFu) * HID + lane];
        }
    }
    out_node[(size_t)w * HID + lane] = acc;
}

// ---------------- standalone pack (mid-tier path) ----------------
__global__ __launch_bounds__(256) void pack_weights(
    const float* __restrict__ W1, const float* __restrict__ W2,
    const float* __restrict__ W3, const float* __restrict__ W4,
    ush* __restrict__ pack)
{
    const int i = blockIdx.x * 256 + threadIdx.x;
    if (i >= 14336) return;
    const float* W; int base;
    if (i < 2048)       { W = W1; base = 0; }
    else if (i < 6144)  { W = W2; base = 2048; }
    else if (i < 10240) { W = W3; base = 6144; }
    else                { W = W4; base = 10240; }
    const int j = i - base;
    const int e = j & 7, l = (j >> 3) & 63, f = j >> 9;
    const int ct = f & 3, kc = f >> 2;
    const int k = kc * 32 + ((l >> 4) << 3) + e;
    const int col = ct * 16 + (l & 15);
    pack[i] = f2b(W[k * HID + col]);
}

// ---------------- MFMA MLP + LayerNorm: r16-proven version (best: 505us) ----------------
template <int APPEND>
__global__ __launch_bounds__(512, 6) void mlp_ln_mfma(
    const float* __restrict__ x,       // [E,32] f32
    const ush* __restrict__ packW,     // 14336 bf16
    const float* __restrict__ b1, const float* __restrict__ b2,
    const float* __restrict__ b3, const float* __restrict__ b4,
    const float* __restrict__ gamma, const float* __restrict__ beta,
    float* __restrict__ out_edge,      // [E,64] f32
    u32* __restrict__ ebf,             // [E][32] bf16 pairs
    int write_bf,
    const int* __restrict__ idx,       // APPEND only
    int* __restrict__ bcur,            // APPEND only
    u32* __restrict__ buf,             // APPEND only
    int E, int N)
{
    __shared__ float sB[6 * HID];                    // 1.5 KB
    __shared__ __align__(16) ush sW[14336];          // 28 KB
    __shared__ __align__(16) ush hbuf[8][16 * 72];   // 18 KB

    const int tid = threadIdx.x;
    const int wave = tid >> 6, lane = tid & 63;

    if (APPEND) {
        const int e = blockIdx.x * 128 + tid;
        if (tid < 128 && e < E) {
            const bool idx64 = sniff_idx64(idx);
            int na, nb;
            if (idx64) { const int4 p = ((const int4*)idx)[e]; na = p.x; nb = p.z; }
            else       { const int2 p = ((const int2*)idx)[e]; na = p.x; nb = p.y; }
            na = min(max(na, 0), N - 1);
            nb = min(max(nb, 0), N - 1);
            const int pa = atomicAdd(&bcur[na >> BSH], 1);
            buf[pa] = ((u32)(na & ((1 << BSH) - 1)) << 29) | (u32)e;
            const int pb = atomicAdd(&bcur[nb >> BSH], 1);
            buf[pb] = ((u32)(nb & ((1 << BSH) - 1)) << 29) | (u32)e;
        }
    }

    {   // stage weights: 1792 uint4 across 512 threads
        const uint4* src = (const uint4*)packW;
        uint4* dst = (uint4*)sW;
        #pragma unroll
        for (int i = 0; i < 4; ++i) {
            const int o = tid + i * 512;
            if (o < 1792) dst[o] = src[o];
        }
    }
    if (tid < HID) {
        sB[tid]           = b1[tid];
        sB[HID + tid]     = b2[tid];
        sB[2 * HID + tid] = b3[tid];
        sB[3 * HID + tid] = b4[tid];
        sB[4 * HID + tid] = gamma[tid];
        sB[5 * HID + tid] = beta[tid];
    }
    __syncthreads();

    const bf16x8* wfrag = (const bf16x8*)sW;

    ush* hb = &hbuf[wave][0];
    const int l15 = lane & 15, lg = lane >> 4;

    const int rowBase = blockIdx.x * 128 + wave * 16;

    const int rr = min(rowBase + l15, E - 1);
    const f32x4* xp = (const f32x4*)(x + (size_t)rr * IN_DIM + lg * 8);
    const f32x4 xa = __builtin_nontemporal_load(xp);
    const f32x4 xb = __builtin_nontemporal_load(xp + 1);
    bf16x8 aL1;
    aL1[0] = (short)f2bh(xa[0]); aL1[1] = (short)f2bh(xa[1]);
    aL1[2] = (short)f2bh(xa[2]); aL1[3] = (short)f2bh(xa[3]);
    aL1[4] = (short)f2bh(xb[0]); aL1[5] = (short)f2bh(xb[1]);
    aL1[6] = (short)f2bh(xb[2]); aL1[7] = (short)f2bh(xb[3]);

    f32x4 acc[4];

    // ---- layer 1 (K=32): 4 MFMAs, B-frags from LDS ----
    #pragma unroll
    for (int ct = 0; ct < 4; ++ct) {
        const float bv = sB[0 * HID + ct * 16 + l15];
        f32x4 c = {bv, bv, bv, bv};
        const bf16x8 wf = wfrag[0 + ct * 64 + lane];
        c = __builtin_amdgcn_mfma_f32_16x16x32_bf16(aL1, wf, c, 0, 0, 0);
        acc[ct] = c;
    }

    #pragma unroll
    for (int ct = 0; ct < 4; ++ct)
        #pragma unroll
        for (int r = 0; r < 4; ++r) {
            float v = acc[ct][r]; v = v > 0.f ? v : 0.f;
            hb[(lg * 4 + r) * 72 + ct * 16 + l15] = (ush)f2bh(v);
        }

    #define LAYER(WBASE, BIDX, RELU_) do {                                  \
        const bf16x8 a0 = *(const bf16x8*)&hb[l15 * 72 + 0 * 32 + lg * 8];  \
        const bf16x8 a1 = *(const bf16x8*)&hb[l15 * 72 + 1 * 32 + lg * 8];  \
        _Pragma("unroll")                                                   \
        for (int ct = 0; ct < 4; ++ct) {                                    \
            const float bv = sB[(BIDX) * HID + ct * 16 + l15];              \
            f32x4 c = {bv, bv, bv, bv};                                     \
            const bf16x8 wlo = wfrag[(WBASE) + ct * 64 + lane];             \
            const bf16x8 whi = wfrag[(WBASE) + (4 + ct) * 64 + lane];       \
            c = __builtin_amdgcn_mfma_f32_16x16x32_bf16(a0, wlo, c, 0, 0, 0); \
            c = __builtin_amdgcn_mfma_f32_16x16x32_bf16(a1, whi, c, 0, 0, 0); \
            acc[ct] = c;                                                    \
        }                                                                   \
        if (RELU_) {                                                        \
            _Pragma("unroll")                                               \
            for (int ct = 0; ct < 4; ++ct)                                  \
                _Pragma("unroll")                                           \
                for (int r = 0; r < 4; ++r) {                               \
                    float v = acc[ct][r]; v = v > 0.f ? v : 0.f;            \
                    hb[(lg * 4 + r) * 72 + ct * 16 + l15] = (ush)f2bh(v);   \
                }                                                           \
        }                                                                   \
    } while (0)

    LAYER(256, 1, 1);
    LAYER(768, 2, 1);
    LAYER(1280, 3, 0);
    #undef LAYER

    float s1[4], s2[4];
    #pragma unroll
    for (int r = 0; r < 4; ++r) {
        float a = acc[0][r] + acc[1][r] + acc[2][r] + acc[3][r];
        float q = acc[0][r] * acc[0][r] + acc[1][r] * acc[1][r]
                + acc[2][r] * acc[2][r] + acc[3][r] * acc[3][r];
        #pragma unroll
        for (int m = 1; m < 16; m <<= 1) {
            a += __shfl_xor(a, m, 64);
            q += __shfl_xor(q, m, 64);
        }
        s1[r] = a; s2[r] = q;
    }

    #pragma unroll
    for (int r = 0; r < 4; ++r) {
        const float mu = s1[r] * (1.0f / HID);
        const float varr = fmaxf(s2[r] * (1.0f / HID) - mu * mu, 0.f);
        const float inv = rsqrtf(varr + LN_EPS);
        const int row = rowBase + lg * 4 + r;
        float* op = out_edge + (size_t)row * HID;
        #pragma unroll
        for (int ct = 0; ct < 4; ++ct) {
            const float g = sB[4 * HID + ct * 16 + l15];
            const float bt = sB[5 * HID + ct * 16 + l15];
            const float val = g * (acc[ct][r] - mu) * inv + bt;
            if (row < E) op[ct * 16 + l15] = val;
            hb[(lg * 4 + r) * 72 + ct * 16 + l15] = (ush)f2bh(val);
        }
    }

    if (write_bf) {
        const int rloc = lane >> 2, ch = lane & 3;
        const int row = rowBase + rloc;
        if (row < E) {
            const u32x4* bsrc = (const u32x4*)&hb[rloc * 72 + ch * 16];
            u32x4* bdst = (u32x4*)(ebf + (size_t)row * 32 + ch * 8);
            bdst[0] = bsrc[0];
            bdst[1] = bsrc[1];
        }
    }
}

// ---------------- fallback: VALU kernel with atomics (ws tiny) ----------------
__global__ __launch_bounds__(256) void mlp_ln_scatter_fb(
    const float* __restrict__ x, const int* __restrict__ idx,
    const float* __restrict__ W1, const float* __restrict__ b1,
    const float* __restrict__ W2, const float* __restrict__ b2,
    const float* __restrict__ W3, const float* __restrict__ b3,
    const float* __restrict__ W4, const float* __restrict__ b4,
    const float* __restrict__ gamma, const float* __restrict__ beta,
    float* __restrict__ out_edge, float* __restrict__ node_acc, int E, int N)
{
    __shared__ float sW1[IN_DIM * HID];
    __shared__ float sW2[HID * HID];
    __shared__ float sW3[HID * HID];
    __shared__ float sW4[HID * HID];
    __shared__ float sB[6 * HID];
    const int tid = threadIdx.x;
    {
        const float4* W1v = (const float4*)W1;
        float4* s1 = (float4*)sW1;
        for (int i = tid; i < IN_DIM * HID / 4; i += 256) s1[i] = W1v[i];
        const float4* W2v = (const float4*)W2;
        const float4* W3v = (const float4*)W3;
        const float4* W4v = (const float4*)W4;
        float4* s2 = (float4*)sW2; float4* s3 = (float4*)sW3; float4* s4 = (float4*)sW4;
        for (int i = tid; i < HID * HID / 4; i += 256) { s2[i] = W2v[i]; s3[i] = W3v[i]; s4[i] = W4v[i]; }
        if (tid < HID) {
            sB[tid] = b1[tid]; sB[HID + tid] = b2[tid]; sB[2 * HID + tid] = b3[tid];
            sB[3 * HID + tid] = b4[tid]; sB[4 * HID + tid] = gamma[tid]; sB[5 * HID + tid] = beta[tid];
        }
    }
    __syncthreads();
    const int e = blockIdx.x * 256 + tid;
    if (e >= E) return;
    float h0[IN_DIM];
    {
        const float4* xv = (const float4*)(x + (size_t)e * IN_DIM);
        #pragma unroll
        for (int c = 0; c < 8; ++c) {
            const float4 v = xv[c];
            h0[c * 4 + 0] = v.x; h0[c * 4 + 1] = v.y; h0[c * 4 + 2] = v.z; h0[c * 4 + 3] = v.w;
        }
    }
    float a[HID], h[HID];
    #pragma unroll
    for (int j = 0; j < HID; ++j) a[j] = sB[j];
    #pragma unroll
    for (int k = 0; k < IN_DIM; ++k) {
        const float hk = h0[k];
        #pragma unroll
        for (int j = 0; j < HID; ++j) a[j] = fmaf(hk, sW1[k * HID + j], a[j]);
    }
    #pragma unroll
    for (int j = 0; j < HID; ++j) h[j] = a[j] > 0.f ? a[j] : 0.f;
    #pragma unroll
    for (int j = 0; j < HID; ++j) a[j] = sB[HID + j];
    #pragma unroll
    for (int k = 0; k < HID; ++k) {
        const float hk = h[k];
        #pragma unroll
        for (int j = 0; j < HID; ++j) a[j] = fmaf(hk, sW2[k * HID + j], a[j]);
    }
    #pragma unroll
    for (int j = 0; j < HID; ++j) h[j] = a[j] > 0.f ? a[j] : 0.f;
    #pragma unroll
    for (int j = 0; j < HID; ++j) a[j] = sB[2 * HID + j];
    #pragma unroll
    for (int k = 0; k < HID; ++k) {
        const float hk = h[k];
        #pragma unroll
        for (int j = 0; j < HID; ++j) a[j] = fmaf(hk, sW3[k * HID + j], a[j]);
    }
    #pragma unroll
    for (int j = 0; j < HID; ++j) h[j] = a[j] > 0.f ? a[j] : 0.f;
    #pragma unroll
    for (int j = 0; j < HID; ++j) a[j] = sB[3 * HID + j];
    #pragma unroll
    for (int k = 0; k < HID; ++k) {
        const float hk = h[k];
        #pragma unroll
        for (int j = 0; j < HID; ++j) a[j] = fmaf(hk, sW4[k * HID + j], a[j]);
    }
    float s = 0.f;
    #pragma unroll
    for (int j = 0; j < HID; ++j) s += a[j];
    const float mu = s * (1.0f / HID);
    float s2 = 0.f;
    #pragma unroll
    for (int j = 0; j < HID; ++j) { const float d = a[j] - mu; s2 += d * d; }
    const float inv = rsqrtf(s2 * (1.0f / HID) + LN_EPS);
    #pragma unroll
    for (int j = 0; j < HID; ++j)
        a[j] = sB[4 * HID + j] * ((a[j] - mu) * inv) + sB[5 * HID + j];
    {
        float4* oe = (float4*)(out_edge + (size_t)e * HID);
        #pragma unroll
        for (int c = 0; c < 16; ++c)
            oe[c] = make_float4(a[c * 4], a[c * 4 + 1], a[c * 4 + 2], a[c * 4 + 3]);
    }
    const bool idx64 = sniff_idx64(idx);
    int na, nb;
    if (idx64) { na = idx[4 * (size_t)e]; nb = idx[4 * (size_t)e + 2]; }
    else       { na = idx[2 * (size_t)e]; nb = idx[2 * (size_t)e + 1]; }
    na = min(max(na, 0), N - 1);
    nb = min(max(nb, 0), N - 1);
    float* pa = node_acc + (size_t)na * HID;
    float* pb = node_acc + (size_t)nb * HID;
    #pragma unroll
    for (int j = 0; j < HID; ++j) {
        unsafeAtomicAdd(pa + j, a[j]);
        unsafeAtomicAdd(pb + j, a[j]);
    }
}

extern "C" void kernel_launch(void* const* d_in, const int* in_sizes, int n_in,
                              void* d_out, int out_size, void* d_ws, size_t ws_size,
                              hipStream_t stream) {
    const float* x     = (const float*)d_in[0];
    const int*   idx   = (const int*)d_in[1];
    const float* W1    = (const float*)d_in[3];
    const float* b1    = (const float*)d_in[4];
    const float* W2    = (const float*)d_in[5];
    const float* b2    = (const float*)d_in[6];
    const float* W3    = (const float*)d_in[7];
    const float* b3    = (const float*)d_in[8];
    const float* W4    = (const float*)d_in[9];
    const float* b4    = (const float*)d_in[10];
    const float* gamma = (const float*)d_in[11];
    const float* beta  = (const float*)d_in[12];

    const int E = in_sizes[0] / IN_DIM;
    const int N = out_size / HID - E;
    const int NB = (N + (1 << BSH) - 1) >> BSH;   // 8-node buckets

    float* out_node = (float*)d_out;
    float* out_edge = out_node + (size_t)N * HID;

    // ---- primary (fixed-capacity) layout:
    //   pack(32KB) | bcur[NB] | nstart[N] | buf[NB<<CSH] | ebf[E*32 u32]
    const size_t bcurOffF   = 32768;
    const size_t nstartOffF = bcurOffF + (((size_t)NB * 4 + 255) & ~255ull);
    const size_t bufOffF    = nstartOffF + (((size_t)N * 4 + 255) & ~255ull);
    const size_t ebfOffF    = (bufOffF + ((size_t)NB << CSH) * 4 + 255) & ~255ull;
    const size_t need_fixed = ebfOffF + (size_t)E * 32 * sizeof(u32);

    // ---- mid-tier (exact CSR layout)
    const size_t bstartOff = 32768;
    const size_t bcurOff   = bstartOff + (((size_t)NB * 4 + 255) & ~255ull);
    const size_t nstartOff = bcurOff + (((size_t)NB * 4 + 255) & ~255ull);
    const size_t bufOff    = nstartOff + (((size_t)N * 4 + 255) & ~255ull);
    const size_t ebfOff    = (bufOff + (size_t)2 * E * sizeof(u32) + 255) & ~255ull;
    const size_t need_base = bufOff + (size_t)2 * E * sizeof(u32);
    const size_t need_bf   = ebfOff + (size_t)E * 32 * sizeof(u32);

    if (ws_size >= need_fixed) {
        // ---------- fixed-capacity path: append fused into MLP, sort fused into gather ----------
        ush* pack   = (ush*)d_ws;
        int* bcur   = (int*)((char*)d_ws + bcurOffF);
        u32* buf    = (u32*)((char*)d_ws + bufOffF);
        u32* ebf    = (u32*)((char*)d_ws + ebfOffF);

        pack_and_init<<<(14336 + 255) / 256, 256, 0, stream>>>(
            W1, W2, W3, W4, pack, bcur, NB);
        mlp_ln_mfma<1><<<(E + 127) / 128, 512, 0, stream>>>(
            x, pack, b1, b2, b3, b4, gamma, beta, out_edge, ebf, 1,
            idx, bcur, buf, E, N);
        sort_gather_bf<<<NB, 512, 0, stream>>>(bcur, buf, ebf, out_node, NB, N);
    } else if (ws_size >= need_base) {
        // ---------- exact-CSR path ----------
        ush* pack   = (ush*)d_ws;
        int* bstart = (int*)((char*)d_ws + bstartOff);
        int* bcur   = (int*)((char*)d_ws + bcurOff);
        int* nstart = (int*)((char*)d_ws + nstartOff);
        u32* buf    = (u32*)((char*)d_ws + bufOff);
        u32* ebf    = (u32*)((char*)d_ws + ebfOff);
        const int use_bf = (ws_size >= need_bf) ? 1 : 0;

        pack_weights<<<(14336 + 255) / 256, 256, 0, stream>>>(W1, W2, W3, W4, pack);
        zero_i32<<<(NB + 255) / 256, 256, 0, stream>>>(bstart, NB);
        bucket_count<<<(E + 255) / 256, 256, 0, stream>>>(idx, bstart, E, N);
        scan_excl2<<<1, 1024, 0, stream>>>(bstart, bcur, NB);
        append_pairs<<<(E + 255) / 256, 256, 0, stream>>>(idx, bcur, buf, E, N);
        bucket_sort<<<(NB + 3) / 4, 256, 0, stream>>>(bstart, bcur, buf, nstart, NB, N);
        mlp_ln_mfma<0><<<(E + 127) / 128, 512, 0, stream>>>(
            x, pack, b1, b2, b3, b4, gamma, beta, out_edge, ebf, use_bf,
            nullptr, nullptr, nullptr, E, N);
        if (use_bf) {
            node_gather_bf<<<(N * 64 + 255) / 256, 256, 0, stream>>>(
                nstart, bstart, bcur, buf, ebf, out_node, N);
        } else {
            node_gather<<<(N * 64 + 255) / 256, 256, 0, stream>>>(
                nstart, bstart, bcur, buf, out_edge, out_node, N);
        }
    } else {
        const int n16 = (int)(((size_t)N * HID * sizeof(float)) / 16);
        zero16<<<(n16 + 255) / 256, 256, 0, stream>>>((uint4*)out_node, n16);
        mlp_ln_scatter_fb<<<(E + 255) / 256, 256, 0, stream>>>(
            x, idx, W1, b1, W2, b2, W3, b3, W4, b4, gamma, beta,
            out_edge, out_node, E, N);
    }
}